// Round 5
// baseline (235.474 us; speedup 1.0000x reference)
//
#include <hip/hip_runtime.h>
#include <hip/hip_bf16.h>
#include <math.h>

#define NH     16
#define HDIM   64
#define SEQ    2048
#define BATCH  2
#define MTOT   (BATCH*SEQ)   // 4096
#define DMODEL 1024
#define HD3    3072          // fused QKV width
#define KVBLK  128

// softmax scale folded into Q at projection time: 1/sqrt(64) * log2(e)
#define QSCALE 0.18033688011112043f
// defer-max threshold, in log2 units (8 nats)
#define THRB   11.54f

typedef __attribute__((ext_vector_type(8))) short  short8;
typedef __attribute__((ext_vector_type(8))) ushort ushort8;
typedef __attribute__((ext_vector_type(4))) ushort ushortx4;
typedef __attribute__((ext_vector_type(4))) float  f32x4;

__device__ __forceinline__ ushort f2b(float f) {
    __hip_bfloat16 h = __float2bfloat16(f);   // RNE
    return *reinterpret_cast<ushort*>(&h);
}
__device__ __forceinline__ uint pack2(float a, float b) {
    return (uint)f2b(a) | ((uint)f2b(b) << 16);
}

// async global->LDS, 16B per lane; LDS dest = wave-uniform base + lane*16
__device__ __forceinline__ void gload_lds16(const void* g, void* l) {
    __builtin_amdgcn_global_load_lds(
        (const __attribute__((address_space(1))) unsigned int*)g,
        (__attribute__((address_space(3))) unsigned int*)l, 16, 0, 0);
}

// ---------------- fp32 -> bf16 convert (vectorized) -------------------------
__global__ __launch_bounds__(256) void cvt_f32_bf16_kernel(
    const float* __restrict__ in, ushort* __restrict__ out, int n8)
{
    const int i = blockIdx.x * 256 + threadIdx.x;
    if (i >= n8) return;
    const float4* p = (const float4*)(in + (size_t)i * 8);
    const float4 v0 = p[0], v1 = p[1];
    ushort8 o;
    o[0] = f2b(v0.x); o[1] = f2b(v0.y); o[2] = f2b(v0.z); o[3] = f2b(v0.w);
    o[4] = f2b(v1.x); o[5] = f2b(v1.y); o[6] = f2b(v1.z); o[7] = f2b(v1.w);
    *(ushort8*)(out + (size_t)i * 8) = o;
}

// ---------------- W [1024][1024] f32  ->  Wt [1024][1024] bf16 (transposed) --
__global__ __launch_bounds__(256) void transpose_w_kernel(
    const float* __restrict__ W, ushort* __restrict__ Wt)
{
    __shared__ float s[64][33];
    const int tid = threadIdx.x;
    const int k0  = blockIdx.y * 32;
    const int n0  = blockIdx.x * 64;
    #pragma unroll
    for (int i = 0; i < 8; ++i) {
        const int idx = tid + i * 256;
        const int n = idx & 63, k = idx >> 6;
        s[n][k] = W[(size_t)(k0 + k) * DMODEL + n0 + n];
    }
    __syncthreads();
    const int n  = tid >> 2;
    const int kc = (tid & 3) * 8;
    ushort8 o;
    #pragma unroll
    for (int j = 0; j < 8; ++j) o[j] = f2b(s[n][kc + j]);
    *(ushort8*)(&Wt[(size_t)(n0 + n) * DMODEL + k0 + kc]) = o;
}

// ---------------- bf16 MFMA GEMM: C[M,N] = A[M,K] @ Bt[N,K]^T (+bias) -------
// Columns n < qcols get scaled by qscale in the epilogue (free Q pre-scale).
template <typename OT>
__global__ __launch_bounds__(256) void gemm_mfma_kernel(
    const ushort* __restrict__ A, const ushort* __restrict__ Bt,
    const float* __restrict__ bias, OT* __restrict__ C,
    int M, int N, int K, int qcols, float qscale)
{
    __shared__ __align__(16) ushort As[128 * 32];
    __shared__ __align__(16) ushort Bs[128 * 32];

    const int tid  = threadIdx.x;
    const int lane = tid & 63;
    const int lr   = lane & 15;
    const int lg   = lane >> 4;
    const int w    = tid >> 6;
    const int wm   = w >> 1, wn = w & 1;

    const int m0 = blockIdx.y * 128;
    const int n0 = blockIdx.x * 128;

    f32x4 acc[4][4];
    #pragma unroll
    for (int mi = 0; mi < 4; ++mi)
        #pragma unroll
        for (int ni = 0; ni < 4; ++ni) acc[mi][ni] = f32x4{0.f, 0.f, 0.f, 0.f};

    for (int kt = 0; kt < K; kt += 32) {
        #pragma unroll
        for (int i = 0; i < 2; ++i) {
            const int ch  = i * 256 + tid;
            const int row = ch >> 2;
            const int ccd = ch & 3;
            const int ccs = ccd ^ ((row >> 1) & 3);
            gload_lds16(&A [(size_t)(m0 + row) * K + kt + ccs * 8], &As[ch * 8]);
            gload_lds16(&Bt[(size_t)(n0 + row) * K + kt + ccs * 8], &Bs[ch * 8]);
        }
        __syncthreads();

        short8 af[4], bf[4];
        #pragma unroll
        for (int mi = 0; mi < 4; ++mi) {
            const int row = wm * 64 + mi * 16 + lr;
            af[mi] = *(const short8*)(&As[row * 32 + (lg ^ ((row >> 1) & 3)) * 8]);
        }
        #pragma unroll
        for (int ni = 0; ni < 4; ++ni) {
            const int row = wn * 64 + ni * 16 + lr;
            bf[ni] = *(const short8*)(&Bs[row * 32 + (lg ^ ((row >> 1) & 3)) * 8]);
        }
        #pragma unroll
        for (int mi = 0; mi < 4; ++mi)
            #pragma unroll
            for (int ni = 0; ni < 4; ++ni)
                acc[mi][ni] = __builtin_amdgcn_mfma_f32_16x16x32_bf16(
                    af[mi], bf[ni], acc[mi][ni], 0, 0, 0);
        __syncthreads();
    }

    #pragma unroll
    for (int mi = 0; mi < 4; ++mi) {
        #pragma unroll
        for (int ni = 0; ni < 4; ++ni) {
            const int n = n0 + wn * 64 + ni * 16 + lr;
            const float bv = bias ? bias[n] : 0.f;
            const float sc = (n < qcols) ? qscale : 1.f;
            #pragma unroll
            for (int r = 0; r < 4; ++r) {
                const int m = m0 + wm * 64 + mi * 16 + lg * 4 + r;
                const float v = (acc[mi][ni][r] + bv) * sc;
                if constexpr (sizeof(OT) == 2)
                    C[(size_t)m * N + n] = f2b(v);
                else
                    C[(size_t)m * N + n] = v;
            }
        }
    }
}

// ---------------- flash attention, swapped-QK^T bf16 MFMA -------------------
// Block: 64 q-rows of one (b,h); 4 waves x 16 rows; KVBLK=128 key tiles,
// processed as two 64-key halves per staging round (halves barrier count).
// Q pre-scaled by 0.125*log2e -> softmax entirely in exp2 domain.
// Defer-max (T13): skip O-rescale while max growth <= THRB bits.
__global__ __launch_bounds__(256) void flash_attn_kernel(
    const ushort* __restrict__ QKV, ushort* __restrict__ Aout)
{
    __shared__ __align__(16) char KsB[KVBLK * 128];       // 16 KB: [key][64d], swz
    __shared__ __align__(16) char VtB[64 * KVBLK * 2];    // 16 KB: V^T [d][128key], swz

    const int tid  = threadIdx.x;
    const int lane = tid & 63;
    const int w    = tid >> 6;
    const int lr   = lane & 15;
    const int lg   = lane >> 4;
    const bool hi  = lg >= 2;

    const int h  = blockIdx.y;
    const int b  = blockIdx.z;
    const int q0 = blockIdx.x * 64;

    const size_t qrow = (size_t)(b * SEQ + q0 + w * 16 + lr);
    short8 qf[2];
    qf[0] = *(const short8*)(&QKV[qrow * HD3 + h * HDIM + 0 * 32 + lg * 8]);
    qf[1] = *(const short8*)(&QKV[qrow * HD3 + h * HDIM + 1 * 32 + lg * 8]);

    f32x4 O[4];
    #pragma unroll
    for (int dn = 0; dn < 4; ++dn) O[dn] = f32x4{0.f, 0.f, 0.f, 0.f};
    float mo = -1e30f, li = 0.f;

    const size_t kbase = (size_t)(b * SEQ) * HD3 + 1024 + h * HDIM;
    const size_t vbase = (size_t)(b * SEQ) * HD3 + 2048 + h * HDIM;

    // staging geometry: cid = tid + i*256 over 1024 16B-chunks per tile
    int rk[4], ck[4], kv[4], cv[4];
    #pragma unroll
    for (int i = 0; i < 4; ++i) {
        const int cid = tid + i * 256;
        rk[i] = cid >> 3;  ck[i] = cid & 7;    // K: row=key 0..127, 8 chunks/row
        kv[i] = cid & 127; cv[i] = cid >> 7;   // V: key 0..127, d-chunk 0..7
    }

    // prologue prefetch (tile 0)
    uint4 kpre[4], vpre[4];
    #pragma unroll
    for (int i = 0; i < 4; ++i) {
        kpre[i] = *(const uint4*)(&QKV[kbase + (size_t)rk[i] * HD3 + ck[i] * 8]);
        vpre[i] = *(const uint4*)(&QKV[vbase + (size_t)kv[i] * HD3 + cv[i] * 8]);
    }

    const int srcA = lr + 16 * ((2 * lg) & 3);
    const int srcB = lr + 16 * ((2 * lg + 1) & 3);

    for (int kt = 0; kt < SEQ; kt += KVBLK) {
        // ---- write staged regs -> LDS
        #pragma unroll
        for (int i = 0; i < 4; ++i) {
            const int by = (rk[i] * 128 + ck[i] * 16) ^ ((rk[i] & 7) << 4);
            *(uint4*)(&KsB[by]) = kpre[i];
        }
        #pragma unroll
        for (int i = 0; i < 4; ++i) {
            const ushort* ve = (const ushort*)&vpre[i];
            #pragma unroll
            for (int j = 0; j < 8; ++j) {
                const int d = cv[i] * 8 + j;
                *(ushort*)(&VtB[(d * 256 + kv[i] * 2) ^ ((d & 7) << 4)]) = ve[j];
            }
        }
        __syncthreads();

        // ---- issue next-tile prefetch (hides under compute)
        if (kt + KVBLK < SEQ) {
            #pragma unroll
            for (int i = 0; i < 4; ++i) {
                kpre[i] = *(const uint4*)(&QKV[kbase + (size_t)(kt + KVBLK + rk[i]) * HD3 + ck[i] * 8]);
                vpre[i] = *(const uint4*)(&QKV[vbase + (size_t)(kt + KVBLK + kv[i]) * HD3 + cv[i] * 8]);
            }
        }

        #pragma unroll
        for (int half = 0; half < 2; ++half) {
            // ---- S^T = K Q^T : p[sub][r] = log2-score(key = half*64+16sub+4lg+r, q=lr)
            float p[4][4];
            __builtin_amdgcn_s_setprio(1);
            #pragma unroll
            for (int sub = 0; sub < 4; ++sub) {
                f32x4 acc = {0.f, 0.f, 0.f, 0.f};
                #pragma unroll
                for (int s = 0; s < 2; ++s) {
                    const int row  = half * 64 + sub * 16 + lr;
                    const int byte = (row * 128 + (s * 4 + lg) * 16) ^ ((row & 7) << 4);
                    short8 kf = *(const short8*)(&KsB[byte]);
                    acc = __builtin_amdgcn_mfma_f32_16x16x32_bf16(kf, qf[s], acc, 0, 0, 0);
                }
                #pragma unroll
                for (int r = 0; r < 4; ++r) p[sub][r] = acc[r];
            }
            __builtin_amdgcn_s_setprio(0);

            // ---- lane-local online softmax, exp2 domain, defer-max
            float rm = p[0][0];
            #pragma unroll
            for (int sub = 0; sub < 4; ++sub)
                #pragma unroll
                for (int r = 0; r < 4; ++r) rm = fmaxf(rm, p[sub][r]);
            rm = fmaxf(rm, __shfl_xor(rm, 16));
            rm = fmaxf(rm, __shfl_xor(rm, 32));
            if (!__all(rm - mo <= THRB)) {
                const float mn = fmaxf(mo, rm);
                const float al = exp2f(mo - mn);
                #pragma unroll
                for (int dn = 0; dn < 4; ++dn)
                    #pragma unroll
                    for (int r = 0; r < 4; ++r) O[dn][r] *= al;
                li *= al;
                mo = mn;
            }
            float rs = 0.f;
            #pragma unroll
            for (int sub = 0; sub < 4; ++sub)
                #pragma unroll
                for (int r = 0; r < 4; ++r) {
                    const float e = exp2f(p[sub][r] - mo);
                    p[sub][r] = e;
                    rs += e;
                }
            rs += __shfl_xor(rs, 16);
            rs += __shfl_xor(rs, 32);
            li += rs;

            // ---- regroup P^T into PV B-frags (keys half*64 + s*32 + 8lg + j)
            short8 pf[2];
            #pragma unroll
            for (int s = 0; s < 2; ++s) {
                const uint P01e = pack2(p[2*s+0][0], p[2*s+0][1]);
                const uint P23e = pack2(p[2*s+0][2], p[2*s+0][3]);
                const uint P01o = pack2(p[2*s+1][0], p[2*s+1][1]);
                const uint P23o = pack2(p[2*s+1][2], p[2*s+1][3]);
                const uint a0 = (uint)__shfl((int)P01e, srcA);
                const uint a1 = (uint)__shfl((int)P01o, srcA);
                const uint b0 = (uint)__shfl((int)P23e, srcA);
                const uint b1 = (uint)__shfl((int)P23o, srcA);
                const uint c0 = (uint)__shfl((int)P01e, srcB);
                const uint c1 = (uint)__shfl((int)P01o, srcB);
                const uint d0 = (uint)__shfl((int)P23e, srcB);
                const uint d1 = (uint)__shfl((int)P23o, srcB);
                union { short8 v; uint u[4]; } un;
                un.u[0] = hi ? a1 : a0;
                un.u[1] = hi ? b1 : b0;
                un.u[2] = hi ? c1 : c0;
                un.u[3] = hi ? d1 : d0;
                pf[s] = un.v;
            }

            // ---- O^T += V^T P^T
            __builtin_amdgcn_s_setprio(1);
            #pragma unroll
            for (int dn = 0; dn < 4; ++dn) {
                #pragma unroll
                for (int s = 0; s < 2; ++s) {
                    const int row  = dn * 16 + lr;
                    const int byte = (row * 256 + ((half * 2 + s) * 4 + lg) * 16) ^ ((row & 7) << 4);
                    short8 vf = *(const short8*)(&VtB[byte]);
                    O[dn] = __builtin_amdgcn_mfma_f32_16x16x32_bf16(vf, pf[s], O[dn], 0, 0, 0);
                }
            }
            __builtin_amdgcn_s_setprio(0);
        }
        __syncthreads();
    }

    // ---- epilogue: O^T lane holds q=lane&15, d = dn*16 + lg*4 + r
    const float inv = 1.f / li;
    const size_t obase = qrow * DMODEL + h * HDIM;
    #pragma unroll
    for (int dn = 0; dn < 4; ++dn) {
        ushortx4 o;
        #pragma unroll
        for (int r = 0; r < 4; ++r) o[r] = f2b(O[dn][r] * inv);
        *(ushortx4*)(&Aout[obase + dn * 16 + lg * 4]) = o;
    }
}

// ---------------------------------------------------------------------------
extern "C" void kernel_launch(void* const* d_in, const int* in_sizes, int n_in,
                              void* d_out, int out_size, void* d_ws, size_t ws_size,
                              hipStream_t stream)
{
    const float* x  = (const float*)d_in[0];
    const float* Wq = (const float*)d_in[1];
    const float* Wk = (const float*)d_in[2];
    const float* Wv = (const float*)d_in[3];
    const float* Wo = (const float*)d_in[4];
    const float* bo = (const float*)d_in[5];
    float* out = (float*)d_out;

    // ws: xb 8MB | Wt_qkv 6MB | Wot 2MB | QKV 24MB    (Ab aliases xb)
    ushort* xb  = (ushort*)d_ws;
    ushort* Wt  = xb  + (size_t)MTOT * DMODEL;
    ushort* Wot = Wt  + (size_t)HD3  * DMODEL;
    ushort* QKV = Wot + (size_t)DMODEL * DMODEL;
    ushort* Ab  = xb;   // x dead after QKV projection

    dim3 blk(256);

    cvt_f32_bf16_kernel<<<dim3(MTOT * DMODEL / 8 / 256), blk, 0, stream>>>(
        x, xb, MTOT * DMODEL / 8);

    dim3 gtr(16, 32);
    transpose_w_kernel<<<gtr, blk, 0, stream>>>(Wq, Wt);
    transpose_w_kernel<<<gtr, blk, 0, stream>>>(Wk, Wt + (size_t)1024 * 1024);
    transpose_w_kernel<<<gtr, blk, 0, stream>>>(Wv, Wt + (size_t)2048 * 1024);
    transpose_w_kernel<<<gtr, blk, 0, stream>>>(Wo, Wot);

    gemm_mfma_kernel<ushort><<<dim3(HD3 / 128, MTOT / 128), blk, 0, stream>>>(
        xb, Wt, nullptr, QKV, MTOT, HD3, DMODEL, DMODEL, QSCALE);

    flash_attn_kernel<<<dim3(SEQ / 64, NH, BATCH), blk, 0, stream>>>(QKV, Ab);

    gemm_mfma_kernel<float><<<dim3(DMODEL / 128, MTOT / 128), blk, 0, stream>>>(
        Ab, Wot, bo, out, MTOT, DMODEL, DMODEL, 0, 1.f);
}

// Round 6
// 181.594 us; speedup vs baseline: 1.2967x; 1.2967x over previous
//
#include <hip/hip_runtime.h>
#include <hip/hip_bf16.h>
#include <math.h>

#define NH     16
#define HDIM   64
#define SEQ    2048
#define BATCH  2
#define MTOT   (BATCH*SEQ)   // 4096
#define DMODEL 1024
#define HD3    3072          // fused QKV width

// softmax scale folded into Q at projection time: 1/sqrt(64) * log2(e)
#define QSCALE 0.18033688011112043f
// defer-max threshold, in log2 units (8 nats)
#define THRB   11.54f

typedef __attribute__((ext_vector_type(8))) short  short8;
typedef __attribute__((ext_vector_type(8))) ushort ushort8;
typedef __attribute__((ext_vector_type(4))) ushort ushortx4;
typedef __attribute__((ext_vector_type(4))) float  f32x4;

__device__ __forceinline__ ushort f2b(float f) {
    __hip_bfloat16 h = __float2bfloat16(f);   // RNE
    return *reinterpret_cast<ushort*>(&h);
}
__device__ __forceinline__ uint pack2(float a, float b) {
    return (uint)f2b(a) | ((uint)f2b(b) << 16);
}

// async global->LDS, 16B per lane; LDS dest = wave-uniform base + lane*16
__device__ __forceinline__ void gload_lds16(const void* g, void* l) {
    __builtin_amdgcn_global_load_lds(
        (const __attribute__((address_space(1))) unsigned int*)g,
        (__attribute__((address_space(3))) unsigned int*)l, 16, 0, 0);
}

// ---------------- fp32 -> bf16 convert (vectorized) -------------------------
__global__ __launch_bounds__(256) void cvt_f32_bf16_kernel(
    const float* __restrict__ in, ushort* __restrict__ out, int n8)
{
    const int i = blockIdx.x * 256 + threadIdx.x;
    if (i >= n8) return;
    const float4* p = (const float4*)(in + (size_t)i * 8);
    const float4 v0 = p[0], v1 = p[1];
    ushort8 o;
    o[0] = f2b(v0.x); o[1] = f2b(v0.y); o[2] = f2b(v0.z); o[3] = f2b(v0.w);
    o[4] = f2b(v1.x); o[5] = f2b(v1.y); o[6] = f2b(v1.z); o[7] = f2b(v1.w);
    *(ushort8*)(out + (size_t)i * 8) = o;
}

// ---------------- W [1024][1024] f32  ->  Wt [1024][1024] bf16 (transposed) --
__global__ __launch_bounds__(256) void transpose_w_kernel(
    const float* __restrict__ W, ushort* __restrict__ Wt)
{
    __shared__ float s[64][33];
    const int tid = threadIdx.x;
    const int k0  = blockIdx.y * 32;
    const int n0  = blockIdx.x * 64;
    #pragma unroll
    for (int i = 0; i < 8; ++i) {
        const int idx = tid + i * 256;
        const int n = idx & 63, k = idx >> 6;
        s[n][k] = W[(size_t)(k0 + k) * DMODEL + n0 + n];
    }
    __syncthreads();
    const int n  = tid >> 2;
    const int kc = (tid & 3) * 8;
    ushort8 o;
    #pragma unroll
    for (int j = 0; j < 8; ++j) o[j] = f2b(s[n][kc + j]);
    *(ushort8*)(&Wt[(size_t)(n0 + n) * DMODEL + k0 + kc]) = o;
}

// ---------------- bf16 MFMA GEMM: C[M,N] = A[M,K] @ Bt[N,K]^T (+bias) -------
// Columns n < qcols get scaled by qscale in the epilogue (free Q pre-scale).
template <typename OT>
__global__ __launch_bounds__(256) void gemm_mfma_kernel(
    const ushort* __restrict__ A, const ushort* __restrict__ Bt,
    const float* __restrict__ bias, OT* __restrict__ C,
    int M, int N, int K, int qcols, float qscale)
{
    __shared__ __align__(16) ushort As[128 * 32];
    __shared__ __align__(16) ushort Bs[128 * 32];

    const int tid  = threadIdx.x;
    const int lane = tid & 63;
    const int lr   = lane & 15;
    const int lg   = lane >> 4;
    const int w    = tid >> 6;
    const int wm   = w >> 1, wn = w & 1;

    const int m0 = blockIdx.y * 128;
    const int n0 = blockIdx.x * 128;

    f32x4 acc[4][4];
    #pragma unroll
    for (int mi = 0; mi < 4; ++mi)
        #pragma unroll
        for (int ni = 0; ni < 4; ++ni) acc[mi][ni] = f32x4{0.f, 0.f, 0.f, 0.f};

    for (int kt = 0; kt < K; kt += 32) {
        #pragma unroll
        for (int i = 0; i < 2; ++i) {
            const int ch  = i * 256 + tid;
            const int row = ch >> 2;
            const int ccd = ch & 3;
            const int ccs = ccd ^ ((row >> 1) & 3);
            gload_lds16(&A [(size_t)(m0 + row) * K + kt + ccs * 8], &As[ch * 8]);
            gload_lds16(&Bt[(size_t)(n0 + row) * K + kt + ccs * 8], &Bs[ch * 8]);
        }
        __syncthreads();

        short8 af[4], bf[4];
        #pragma unroll
        for (int mi = 0; mi < 4; ++mi) {
            const int row = wm * 64 + mi * 16 + lr;
            af[mi] = *(const short8*)(&As[row * 32 + (lg ^ ((row >> 1) & 3)) * 8]);
        }
        #pragma unroll
        for (int ni = 0; ni < 4; ++ni) {
            const int row = wn * 64 + ni * 16 + lr;
            bf[ni] = *(const short8*)(&Bs[row * 32 + (lg ^ ((row >> 1) & 3)) * 8]);
        }
        #pragma unroll
        for (int mi = 0; mi < 4; ++mi)
            #pragma unroll
            for (int ni = 0; ni < 4; ++ni)
                acc[mi][ni] = __builtin_amdgcn_mfma_f32_16x16x32_bf16(
                    af[mi], bf[ni], acc[mi][ni], 0, 0, 0);
        __syncthreads();
    }

    #pragma unroll
    for (int mi = 0; mi < 4; ++mi) {
        #pragma unroll
        for (int ni = 0; ni < 4; ++ni) {
            const int n = n0 + wn * 64 + ni * 16 + lr;
            const float bv = bias ? bias[n] : 0.f;
            const float sc = (n < qcols) ? qscale : 1.f;
            #pragma unroll
            for (int r = 0; r < 4; ++r) {
                const int m = m0 + wm * 64 + mi * 16 + lg * 4 + r;
                const float v = (acc[mi][ni][r] + bv) * sc;
                if constexpr (sizeof(OT) == 2)
                    C[(size_t)m * N + n] = f2b(v);
                else
                    C[(size_t)m * N + n] = v;
            }
        }
    }
}

// ---------------- flash attention, swapped-QK^T bf16 MFMA -------------------
// Round-4 structure (KVBLK=64, 16 KB LDS, reg-prefetch one tile ahead)
// + exp2-domain softmax (Q pre-scaled by 0.125*log2e in GEMM epilogue)
// + defer-max (T13, THR=8 nats) + s_setprio around MFMA clusters (T5).
__global__ __launch_bounds__(256) void flash_attn_kernel(
    const ushort* __restrict__ QKV, ushort* __restrict__ Aout)
{
    __shared__ __align__(16) char KsB[64 * 128];   // 8 KB, XOR-swizzled
    __shared__ __align__(16) char VtB[64 * 128];   // 8 KB, V^T [d][key] swizzled

    const int tid  = threadIdx.x;
    const int lane = tid & 63;
    const int w    = tid >> 6;
    const int lr   = lane & 15;
    const int lg   = lane >> 4;
    const bool hi  = lg >= 2;

    const int h  = blockIdx.y;
    const int b  = blockIdx.z;
    const int q0 = blockIdx.x * 64;

    const size_t qrow = (size_t)(b * SEQ + q0 + w * 16 + lr);
    short8 qf[2];
    qf[0] = *(const short8*)(&QKV[qrow * HD3 + h * HDIM + 0 * 32 + lg * 8]);
    qf[1] = *(const short8*)(&QKV[qrow * HD3 + h * HDIM + 1 * 32 + lg * 8]);

    f32x4 O[4];
    #pragma unroll
    for (int dn = 0; dn < 4; ++dn) O[dn] = f32x4{0.f, 0.f, 0.f, 0.f};
    float mo = -1e30f, li = 0.f;

    const size_t kbase = (size_t)(b * SEQ) * HD3 + 1024 + h * HDIM;
    const size_t vbase = (size_t)(b * SEQ) * HD3 + 2048 + h * HDIM;

    // staging geometry (per thread, fixed): 512 16B-chunks per 64x64 tile
    const int rk0 = tid >> 3,          ck0 = tid & 7;
    const int rk1 = (tid + 256) >> 3,  ck1 = (tid + 256) & 7;
    const int kv0 = tid & 63,          cv0 = tid >> 6;
    const int kv1 = (tid + 256) & 63,  cv1 = (tid + 256) >> 6;

    // prologue prefetch (tile 0)
    uint4 kpre0 = *(const uint4*)(&QKV[kbase + (size_t)rk0 * HD3 + ck0 * 8]);
    uint4 kpre1 = *(const uint4*)(&QKV[kbase + (size_t)rk1 * HD3 + ck1 * 8]);
    uint4 vpre0 = *(const uint4*)(&QKV[vbase + (size_t)kv0 * HD3 + cv0 * 8]);
    uint4 vpre1 = *(const uint4*)(&QKV[vbase + (size_t)kv1 * HD3 + cv1 * 8]);

    const int srcA = lr + 16 * ((2 * lg) & 3);
    const int srcB = lr + 16 * ((2 * lg + 1) & 3);

    for (int kt = 0; kt < SEQ; kt += 64) {
        // ---- write staged regs -> LDS
        {
            const int by0 = (rk0 * 128 + ck0 * 16) ^ ((rk0 & 7) << 4);
            const int by1 = (rk1 * 128 + ck1 * 16) ^ ((rk1 & 7) << 4);
            *(uint4*)(&KsB[by0]) = kpre0;
            *(uint4*)(&KsB[by1]) = kpre1;
            const ushort* ve0 = (const ushort*)&vpre0;
            const ushort* ve1 = (const ushort*)&vpre1;
            #pragma unroll
            for (int j = 0; j < 8; ++j) {   // d&7 == j  (d = cv*8 + j)
                const int d0 = cv0 * 8 + j, d1 = cv1 * 8 + j;
                *(ushort*)(&VtB[(d0 * 128 + kv0 * 2) ^ (j << 4)]) = ve0[j];
                *(ushort*)(&VtB[(d1 * 128 + kv1 * 2) ^ (j << 4)]) = ve1[j];
            }
        }
        __syncthreads();

        // ---- issue next-tile prefetch (lands during compute below)
        {
            const int ktn = (kt + 64 < SEQ) ? kt + 64 : 0;   // clamp (dummy reload)
            kpre0 = *(const uint4*)(&QKV[kbase + (size_t)(ktn + rk0) * HD3 + ck0 * 8]);
            kpre1 = *(const uint4*)(&QKV[kbase + (size_t)(ktn + rk1) * HD3 + ck1 * 8]);
            vpre0 = *(const uint4*)(&QKV[vbase + (size_t)(ktn + kv0) * HD3 + cv0 * 8]);
            vpre1 = *(const uint4*)(&QKV[vbase + (size_t)(ktn + kv1) * HD3 + cv1 * 8]);
        }

        // ---- S^T = K Q^T : p[sub][r] = log2-score(key=16*sub+4*lg+r, q=lr)
        float p[4][4];
        __builtin_amdgcn_s_setprio(1);
        #pragma unroll
        for (int sub = 0; sub < 4; ++sub) {
            f32x4 acc = {0.f, 0.f, 0.f, 0.f};
            #pragma unroll
            for (int s = 0; s < 2; ++s) {
                const int row  = sub * 16 + lr;
                const int byte = (row * 128 + (s * 4 + lg) * 16) ^ ((row & 7) << 4);
                short8 kf = *(const short8*)(&KsB[byte]);
                acc = __builtin_amdgcn_mfma_f32_16x16x32_bf16(kf, qf[s], acc, 0, 0, 0);
            }
            #pragma unroll
            for (int r = 0; r < 4; ++r) p[sub][r] = acc[r];
        }
        __builtin_amdgcn_s_setprio(0);

        // ---- lane-local online softmax, exp2 domain, defer-max
        float rm = p[0][0];
        #pragma unroll
        for (int sub = 0; sub < 4; ++sub)
            #pragma unroll
            for (int r = 0; r < 4; ++r) rm = fmaxf(rm, p[sub][r]);
        rm = fmaxf(rm, __shfl_xor(rm, 16));
        rm = fmaxf(rm, __shfl_xor(rm, 32));
        if (!__all(rm - mo <= THRB)) {
            const float mn = fmaxf(mo, rm);
            const float al = exp2f(mo - mn);
            #pragma unroll
            for (int dn = 0; dn < 4; ++dn)
                #pragma unroll
                for (int r = 0; r < 4; ++r) O[dn][r] *= al;
            li *= al;
            mo = mn;
        }
        float rs = 0.f;
        #pragma unroll
        for (int sub = 0; sub < 4; ++sub)
            #pragma unroll
            for (int r = 0; r < 4; ++r) {
                const float e = exp2f(p[sub][r] - mo);
                p[sub][r] = e;
                rs += e;
            }
        rs += __shfl_xor(rs, 16);
        rs += __shfl_xor(rs, 32);
        li += rs;

        // ---- regroup P^T into PV B-frags (keys s*32 + 8*lg + j per lane)
        short8 pf[2];
        #pragma unroll
        for (int s = 0; s < 2; ++s) {
            const uint P01e = pack2(p[2*s+0][0], p[2*s+0][1]);
            const uint P23e = pack2(p[2*s+0][2], p[2*s+0][3]);
            const uint P01o = pack2(p[2*s+1][0], p[2*s+1][1]);
            const uint P23o = pack2(p[2*s+1][2], p[2*s+1][3]);
            const uint a0 = (uint)__shfl((int)P01e, srcA);
            const uint a1 = (uint)__shfl((int)P01o, srcA);
            const uint b0 = (uint)__shfl((int)P23e, srcA);
            const uint b1 = (uint)__shfl((int)P23o, srcA);
            const uint c0 = (uint)__shfl((int)P01e, srcB);
            const uint c1 = (uint)__shfl((int)P01o, srcB);
            const uint d0 = (uint)__shfl((int)P23e, srcB);
            const uint d1 = (uint)__shfl((int)P23o, srcB);
            union { short8 v; uint u[4]; } un;
            un.u[0] = hi ? a1 : a0;
            un.u[1] = hi ? b1 : b0;
            un.u[2] = hi ? c1 : c0;
            un.u[3] = hi ? d1 : d0;
            pf[s] = un.v;
        }

        // ---- O^T += V^T P^T
        __builtin_amdgcn_s_setprio(1);
        #pragma unroll
        for (int dn = 0; dn < 4; ++dn) {
            #pragma unroll
            for (int s = 0; s < 2; ++s) {
                const int row  = dn * 16 + lr;
                const int byte = (row * 128 + (s * 4 + lg) * 16) ^ ((row & 7) << 4);
                short8 vf = *(const short8*)(&VtB[byte]);
                O[dn] = __builtin_amdgcn_mfma_f32_16x16x32_bf16(vf, pf[s], O[dn], 0, 0, 0);
            }
        }
        __builtin_amdgcn_s_setprio(0);
        __syncthreads();
    }

    // ---- epilogue: O^T lane holds q=lane&15, d = dn*16 + lg*4 + r
    const float inv = 1.f / li;
    const size_t obase = qrow * DMODEL + h * HDIM;
    #pragma unroll
    for (int dn = 0; dn < 4; ++dn) {
        ushortx4 o;
        #pragma unroll
        for (int r = 0; r < 4; ++r) o[r] = f2b(O[dn][r] * inv);
        *(ushortx4*)(&Aout[obase + dn * 16 + lg * 4]) = o;
    }
}

// ---------------------------------------------------------------------------
extern "C" void kernel_launch(void* const* d_in, const int* in_sizes, int n_in,
                              void* d_out, int out_size, void* d_ws, size_t ws_size,
                              hipStream_t stream)
{
    const float* x  = (const float*)d_in[0];
    const float* Wq = (const float*)d_in[1];
    const float* Wk = (const float*)d_in[2];
    const float* Wv = (const float*)d_in[3];
    const float* Wo = (const float*)d_in[4];
    const float* bo = (const float*)d_in[5];
    float* out = (float*)d_out;

    // ws: xb 8MB | Wt_qkv 6MB | Wot 2MB | QKV 24MB    (Ab aliases xb)
    ushort* xb  = (ushort*)d_ws;
    ushort* Wt  = xb  + (size_t)MTOT * DMODEL;
    ushort* Wot = Wt  + (size_t)HD3  * DMODEL;
    ushort* QKV = Wot + (size_t)DMODEL * DMODEL;
    ushort* Ab  = xb;   // x dead after QKV projection

    dim3 blk(256);

    cvt_f32_bf16_kernel<<<dim3(MTOT * DMODEL / 8 / 256), blk, 0, stream>>>(
        x, xb, MTOT * DMODEL / 8);

    dim3 gtr(16, 32);
    transpose_w_kernel<<<gtr, blk, 0, stream>>>(Wq, Wt);
    transpose_w_kernel<<<gtr, blk, 0, stream>>>(Wk, Wt + (size_t)1024 * 1024);
    transpose_w_kernel<<<gtr, blk, 0, stream>>>(Wv, Wt + (size_t)2048 * 1024);
    transpose_w_kernel<<<gtr, blk, 0, stream>>>(Wo, Wot);

    gemm_mfma_kernel<ushort><<<dim3(HD3 / 128, MTOT / 128), blk, 0, stream>>>(
        xb, Wt, nullptr, QKV, MTOT, HD3, DMODEL, DMODEL, QSCALE);

    flash_attn_kernel<<<dim3(SEQ / 64, NH, BATCH), blk, 0, stream>>>(QKV, Ab);

    gemm_mfma_kernel<float><<<dim3(DMODEL / 128, MTOT / 128), blk, 0, stream>>>(
        Ab, Wot, bo, out, MTOT, DMODEL, DMODEL, 0, 1.f);
}

// Round 7
// 176.026 us; speedup vs baseline: 1.3377x; 1.0316x over previous
//
#include <hip/hip_runtime.h>
#include <hip/hip_bf16.h>
#include <math.h>

#define NH     16
#define HDIM   64
#define SEQ    2048
#define BATCH  2
#define MTOT   (BATCH*SEQ)   // 4096
#define DMODEL 1024
#define HD3    3072          // fused QKV projection width (compute)
#define QKW    2048          // stored Q|K row width (V diverted to Vt)

// softmax scale folded into Q at projection time: 1/sqrt(64) * log2(e)
#define QSCALE 0.18033688011112043f
// defer-max threshold, in log2 units (8 nats)
#define THRB   11.54f

typedef __attribute__((ext_vector_type(8))) short  short8;
typedef __attribute__((ext_vector_type(8))) ushort ushort8;
typedef __attribute__((ext_vector_type(4))) ushort ushortx4;
typedef __attribute__((ext_vector_type(4))) float  f32x4;

__device__ __forceinline__ ushort f2b(float f) {
    __hip_bfloat16 h = __float2bfloat16(f);   // RNE
    return *reinterpret_cast<ushort*>(&h);
}
// packed 2xbf16 convert (T12): single VALU op, no builtin on gfx950
__device__ __forceinline__ uint cvtpk(float a, float b) {
    uint r;
    asm("v_cvt_pk_bf16_f32 %0, %1, %2" : "=v"(r) : "v"(a), "v"(b));
    return r;
}

// async global->LDS, 16B per lane; LDS dest = wave-uniform base + lane*16
__device__ __forceinline__ void gload_lds16(const void* g, void* l) {
    __builtin_amdgcn_global_load_lds(
        (const __attribute__((address_space(1))) unsigned int*)g,
        (__attribute__((address_space(3))) unsigned int*)l, 16, 0, 0);
}

// ---------------- fp32 -> bf16 convert (vectorized) -------------------------
__global__ __launch_bounds__(256) void cvt_f32_bf16_kernel(
    const float* __restrict__ in, ushort* __restrict__ out, int n8)
{
    const int i = blockIdx.x * 256 + threadIdx.x;
    if (i >= n8) return;
    const float4* p = (const float4*)(in + (size_t)i * 8);
    const float4 v0 = p[0], v1 = p[1];
    ushort8 o;
    o[0] = f2b(v0.x); o[1] = f2b(v0.y); o[2] = f2b(v0.z); o[3] = f2b(v0.w);
    o[4] = f2b(v1.x); o[5] = f2b(v1.y); o[6] = f2b(v1.z); o[7] = f2b(v1.w);
    *(ushort8*)(out + (size_t)i * 8) = o;
}

// ---------------- W [1024][1024] f32  ->  Wt [1024][1024] bf16 (transposed) --
__global__ __launch_bounds__(256) void transpose_w_kernel(
    const float* __restrict__ W, ushort* __restrict__ Wt)
{
    __shared__ float s[64][33];
    const int tid = threadIdx.x;
    const int k0  = blockIdx.y * 32;
    const int n0  = blockIdx.x * 64;
    #pragma unroll
    for (int i = 0; i < 8; ++i) {
        const int idx = tid + i * 256;
        const int n = idx & 63, k = idx >> 6;
        s[n][k] = W[(size_t)(k0 + k) * DMODEL + n0 + n];
    }
    __syncthreads();
    const int n  = tid >> 2;
    const int kc = (tid & 3) * 8;
    ushort8 o;
    #pragma unroll
    for (int j = 0; j < 8; ++j) o[j] = f2b(s[n][kc + j]);
    *(ushort8*)(&Wt[(size_t)(n0 + n) * DMODEL + k0 + kc]) = o;
}

// ---------------- bf16 MFMA GEMM: C[M,N] = A[M,K] @ Bt[N,K]^T (+bias) -------
// n < qcols scaled by qscale. If Vt != null, columns n >= 2048 (the V head
// outputs) are stored TRANSPOSED into Vt[b][h][d][s] instead of C.
template <typename OT>
__global__ __launch_bounds__(256) void gemm_mfma_kernel(
    const ushort* __restrict__ A, const ushort* __restrict__ Bt,
    const float* __restrict__ bias, OT* __restrict__ C,
    ushort* __restrict__ Vt,
    int M, int N, int K, int ldc, int qcols, float qscale)
{
    __shared__ __align__(16) ushort As[128 * 32];
    __shared__ __align__(16) ushort Bs[128 * 32];

    const int tid  = threadIdx.x;
    const int lane = tid & 63;
    const int lr   = lane & 15;
    const int lg   = lane >> 4;
    const int w    = tid >> 6;
    const int wm   = w >> 1, wn = w & 1;

    const int m0 = blockIdx.y * 128;
    const int n0 = blockIdx.x * 128;

    f32x4 acc[4][4];
    #pragma unroll
    for (int mi = 0; mi < 4; ++mi)
        #pragma unroll
        for (int ni = 0; ni < 4; ++ni) acc[mi][ni] = f32x4{0.f, 0.f, 0.f, 0.f};

    for (int kt = 0; kt < K; kt += 32) {
        #pragma unroll
        for (int i = 0; i < 2; ++i) {
            const int ch  = i * 256 + tid;
            const int row = ch >> 2;
            const int ccd = ch & 3;
            const int ccs = ccd ^ ((row >> 1) & 3);
            gload_lds16(&A [(size_t)(m0 + row) * K + kt + ccs * 8], &As[ch * 8]);
            gload_lds16(&Bt[(size_t)(n0 + row) * K + kt + ccs * 8], &Bs[ch * 8]);
        }
        __syncthreads();

        short8 af[4], bf[4];
        #pragma unroll
        for (int mi = 0; mi < 4; ++mi) {
            const int row = wm * 64 + mi * 16 + lr;
            af[mi] = *(const short8*)(&As[row * 32 + (lg ^ ((row >> 1) & 3)) * 8]);
        }
        #pragma unroll
        for (int ni = 0; ni < 4; ++ni) {
            const int row = wn * 64 + ni * 16 + lr;
            bf[ni] = *(const short8*)(&Bs[row * 32 + (lg ^ ((row >> 1) & 3)) * 8]);
        }
        #pragma unroll
        for (int mi = 0; mi < 4; ++mi)
            #pragma unroll
            for (int ni = 0; ni < 4; ++ni)
                acc[mi][ni] = __builtin_amdgcn_mfma_f32_16x16x32_bf16(
                    af[mi], bf[ni], acc[mi][ni], 0, 0, 0);
        __syncthreads();
    }

    if (Vt != nullptr && n0 >= 2048) {
        // V head outputs -> Vt[b][h][d][s]  (r-loop spans 4 consecutive tokens)
        #pragma unroll
        for (int mi = 0; mi < 4; ++mi) {
            const int mb = m0 + wm * 64 + mi * 16 + lg * 4;
            const int bb = mb >> 11, ss = mb & 2047;
            #pragma unroll
            for (int ni = 0; ni < 4; ++ni) {
                const int n  = n0 + wn * 64 + ni * 16 + lr - 2048;
                const int h  = n >> 6, dd = n & 63;
                ushortx4 o;
                #pragma unroll
                for (int r = 0; r < 4; ++r) o[r] = f2b(acc[mi][ni][r]);
                *(ushortx4*)(&Vt[(((size_t)bb * NH + h) * HDIM + dd) * SEQ + ss]) = o;
            }
        }
        return;
    }

    #pragma unroll
    for (int mi = 0; mi < 4; ++mi) {
        #pragma unroll
        for (int ni = 0; ni < 4; ++ni) {
            const int n = n0 + wn * 64 + ni * 16 + lr;
            const float bv = bias ? bias[n] : 0.f;
            const float sc = (n < qcols) ? qscale : 1.f;
            #pragma unroll
            for (int r = 0; r < 4; ++r) {
                const int m = m0 + wm * 64 + mi * 16 + lg * 4 + r;
                const float v = (acc[mi][ni][r] + bv) * sc;
                if constexpr (sizeof(OT) == 2)
                    C[(size_t)m * ldc + n] = f2b(v);
                else
                    C[(size_t)m * ldc + n] = v;
            }
        }
    }
}

// ---------------- flash attention, swapped-QK^T bf16 MFMA -------------------
// QK buffer [MTOT][2048] (Q | K per row, Q pre-scaled by 0.125*log2e);
// Vt[b][h][d][s] pre-transposed. K and V^T tiles are both [64 rows][64 elems]
// with row stride 2048 elems -> staged by global_load_lds (linear LDS dest,
// inverse-swizzled source chunk = c ^ (row&7)), double-buffered, ONE barrier
// per tile. Softmax in exp2 domain with defer-max; P packed via cvt_pk.
__global__ __launch_bounds__(256) void flash_attn_kernel(
    const ushort* __restrict__ QK, const ushort* __restrict__ Vt,
    ushort* __restrict__ Aout)
{
    __shared__ __align__(16) char LDS[2][16384];   // per buf: K 8KB | V^T 8KB

    const int tid  = threadIdx.x;
    const int lane = tid & 63;
    const int w    = tid >> 6;
    const int lr   = lane & 15;
    const int lg   = lane >> 4;
    const bool hiq = lg >= 2;

    const int h  = blockIdx.y;
    const int b  = blockIdx.z;
    const int q0 = blockIdx.x * 64;

    const size_t qbase = ((size_t)(b * SEQ + q0 + w * 16 + lr)) * QKW + h * HDIM;
    short8 qf[2];
    qf[0] = *(const short8*)(&QK[qbase + 0 * 32 + lg * 8]);
    qf[1] = *(const short8*)(&QK[qbase + 1 * 32 + lg * 8]);

    f32x4 O[4];
    #pragma unroll
    for (int dn = 0; dn < 4; ++dn) O[dn] = f32x4{0.f, 0.f, 0.f, 0.f};
    float mo = -1e30f, li = 0.f;

    const size_t kbase  = (size_t)b * SEQ * QKW + 1024 + h * HDIM;  // +(kt+row)*QKW
    const size_t vtbase = ((size_t)(b * NH + h)) * HDIM * SEQ;      // + d*SEQ + kt

    // staging geometry: chunk c = tid (+256); row = c>>3; src = (c&7)^(row&7)
    const int r0   = tid >> 3;
    const int s0   = (tid & 7) ^ (r0 & 7);
    const size_t off0 = (size_t)r0 * QKW + s0 * 8;          // rows 0..31
    const size_t off1 = off0 + (size_t)32 * QKW;            // rows 32..63 (same s)

    // prologue: stage tile 0 into buf 0
    {
        const ushort* Kg = QK + kbase;
        const ushort* Vg = Vt + vtbase;
        gload_lds16(Kg + off0, &LDS[0][tid * 16]);
        gload_lds16(Kg + off1, &LDS[0][4096 + tid * 16]);
        gload_lds16(Vg + off0, &LDS[0][8192 + tid * 16]);
        gload_lds16(Vg + off1, &LDS[0][12288 + tid * 16]);
    }

    const int srcA = lr + 16 * ((2 * lg) & 3);
    const int srcB = lr + 16 * ((2 * lg + 1) & 3);

    for (int kt = 0; kt < SEQ; kt += 64) {
        const int cur = (kt >> 6) & 1;
        __syncthreads();   // drains vmcnt: buf[cur] ready; prev reads of buf[cur^1] done

        // ---- issue next tile into buf[cur^1] (in flight during compute)
        if (kt + 64 < SEQ) {
            const ushort* Kg = QK + kbase + (size_t)(kt + 64) * QKW;
            const ushort* Vg = Vt + vtbase + (kt + 64);
            char* Lb = &LDS[cur ^ 1][0];
            gload_lds16(Kg + off0, Lb + tid * 16);
            gload_lds16(Kg + off1, Lb + 4096 + tid * 16);
            gload_lds16(Vg + off0, Lb + 8192 + tid * 16);
            gload_lds16(Vg + off1, Lb + 12288 + tid * 16);
        }

        const char* Kb = &LDS[cur][0];
        const char* Vb = &LDS[cur][8192];

        // ---- S^T = K Q^T : p[sub][r] = log2-score(key=16*sub+4*lg+r, q=lr)
        float p[4][4];
        __builtin_amdgcn_s_setprio(1);
        #pragma unroll
        for (int sub = 0; sub < 4; ++sub) {
            f32x4 acc = {0.f, 0.f, 0.f, 0.f};
            #pragma unroll
            for (int s = 0; s < 2; ++s) {
                const int row  = sub * 16 + lr;
                const int byte = (row * 128 + (s * 4 + lg) * 16) ^ ((row & 7) << 4);
                short8 kf = *(const short8*)(&Kb[byte]);
                acc = __builtin_amdgcn_mfma_f32_16x16x32_bf16(kf, qf[s], acc, 0, 0, 0);
            }
            #pragma unroll
            for (int r = 0; r < 4; ++r) p[sub][r] = acc[r];
        }
        __builtin_amdgcn_s_setprio(0);

        // ---- lane-local online softmax, exp2 domain, defer-max
        float rm = p[0][0];
        #pragma unroll
        for (int sub = 0; sub < 4; ++sub)
            #pragma unroll
            for (int r = 0; r < 4; ++r) rm = fmaxf(rm, p[sub][r]);
        rm = fmaxf(rm, __shfl_xor(rm, 16));
        rm = fmaxf(rm, __shfl_xor(rm, 32));
        if (!__all(rm - mo <= THRB)) {
            const float mn = fmaxf(mo, rm);
            const float al = exp2f(mo - mn);
            #pragma unroll
            for (int dn = 0; dn < 4; ++dn)
                #pragma unroll
                for (int r = 0; r < 4; ++r) O[dn][r] *= al;
            li *= al;
            mo = mn;
        }
        float rs = 0.f;
        #pragma unroll
        for (int sub = 0; sub < 4; ++sub)
            #pragma unroll
            for (int r = 0; r < 4; ++r) {
                const float e = exp2f(p[sub][r] - mo);
                p[sub][r] = e;
                rs += e;
            }
        rs += __shfl_xor(rs, 16);
        rs += __shfl_xor(rs, 32);
        li += rs;

        // ---- regroup P^T into PV B-frags (keys s*32 + 8*lg + j per lane)
        short8 pf[2];
        #pragma unroll
        for (int s = 0; s < 2; ++s) {
            const uint P01e = cvtpk(p[2*s+0][0], p[2*s+0][1]);
            const uint P23e = cvtpk(p[2*s+0][2], p[2*s+0][3]);
            const uint P01o = cvtpk(p[2*s+1][0], p[2*s+1][1]);
            const uint P23o = cvtpk(p[2*s+1][2], p[2*s+1][3]);
            const uint a0 = (uint)__shfl((int)P01e, srcA);
            const uint a1 = (uint)__shfl((int)P01o, srcA);
            const uint b0 = (uint)__shfl((int)P23e, srcA);
            const uint b1 = (uint)__shfl((int)P23o, srcA);
            const uint c0 = (uint)__shfl((int)P01e, srcB);
            const uint c1 = (uint)__shfl((int)P01o, srcB);
            const uint d0 = (uint)__shfl((int)P23e, srcB);
            const uint d1 = (uint)__shfl((int)P23o, srcB);
            union { short8 v; uint u[4]; } un;
            un.u[0] = hiq ? a1 : a0;
            un.u[1] = hiq ? b1 : b0;
            un.u[2] = hiq ? c1 : c0;
            un.u[3] = hiq ? d1 : d0;
            pf[s] = un.v;
        }

        // ---- O^T += V^T P^T
        __builtin_amdgcn_s_setprio(1);
        #pragma unroll
        for (int dn = 0; dn < 4; ++dn) {
            #pragma unroll
            for (int s = 0; s < 2; ++s) {
                const int row  = dn * 16 + lr;
                const int byte = (row * 128 + (s * 4 + lg) * 16) ^ ((row & 7) << 4);
                short8 vf = *(const short8*)(&Vb[byte]);
                O[dn] = __builtin_amdgcn_mfma_f32_16x16x32_bf16(vf, pf[s], O[dn], 0, 0, 0);
            }
        }
        __builtin_amdgcn_s_setprio(0);
    }

    // ---- epilogue: O^T lane holds q=lane&15, d = dn*16 + lg*4 + r
    const float inv = 1.f / li;
    const size_t obase = ((size_t)(b * SEQ + q0 + w * 16 + lr)) * DMODEL + h * HDIM;
    #pragma unroll
    for (int dn = 0; dn < 4; ++dn) {
        ushortx4 o;
        #pragma unroll
        for (int r = 0; r < 4; ++r) o[r] = f2b(O[dn][r] * inv);
        *(ushortx4*)(&Aout[obase + dn * 16 + lg * 4]) = o;
    }
}

// ---------------------------------------------------------------------------
extern "C" void kernel_launch(void* const* d_in, const int* in_sizes, int n_in,
                              void* d_out, int out_size, void* d_ws, size_t ws_size,
                              hipStream_t stream)
{
    const float* x  = (const float*)d_in[0];
    const float* Wq = (const float*)d_in[1];
    const float* Wk = (const float*)d_in[2];
    const float* Wv = (const float*)d_in[3];
    const float* Wo = (const float*)d_in[4];
    const float* bo = (const float*)d_in[5];
    float* out = (float*)d_out;

    // ws: xb 8MB | Wt_qkv 6MB | Wot 2MB | QK 16MB | Vt 8MB   (Ab aliases xb)
    ushort* xb  = (ushort*)d_ws;
    ushort* Wt  = xb  + (size_t)MTOT * DMODEL;
    ushort* Wot = Wt  + (size_t)HD3  * DMODEL;
    ushort* QK  = Wot + (size_t)DMODEL * DMODEL;
    ushort* Vt  = QK  + (size_t)MTOT * QKW;
    ushort* Ab  = xb;   // x dead after QKV projection

    dim3 blk(256);

    cvt_f32_bf16_kernel<<<dim3(MTOT * DMODEL / 8 / 256), blk, 0, stream>>>(
        x, xb, MTOT * DMODEL / 8);

    dim3 gtr(16, 32);
    transpose_w_kernel<<<gtr, blk, 0, stream>>>(Wq, Wt);
    transpose_w_kernel<<<gtr, blk, 0, stream>>>(Wk, Wt + (size_t)1024 * 1024);
    transpose_w_kernel<<<gtr, blk, 0, stream>>>(Wv, Wt + (size_t)2048 * 1024);
    transpose_w_kernel<<<gtr, blk, 0, stream>>>(Wo, Wot);

    // QKV projection: Q|K -> QK (ldc=2048, Q scaled), V -> Vt transposed
    gemm_mfma_kernel<ushort><<<dim3(HD3 / 128, MTOT / 128), blk, 0, stream>>>(
        xb, Wt, nullptr, QK, Vt, MTOT, HD3, DMODEL, QKW, DMODEL, QSCALE);

    flash_attn_kernel<<<dim3(SEQ / 64, NH, BATCH), blk, 0, stream>>>(QK, Vt, Ab);

    gemm_mfma_kernel<float><<<dim3(DMODEL / 128, MTOT / 128), blk, 0, stream>>>(
        Ab, Wot, bo, out, nullptr, MTOT, DMODEL, DMODEL, DMODEL, 0, 1.f);
}